// Round 10
// baseline (369.234 us; speedup 1.0000x reference)
//
#include <hip/hip_runtime.h>
#include <stdint.h>

typedef __attribute__((ext_vector_type(8))) short short8;
typedef __attribute__((ext_vector_type(4))) float f32x4;
typedef __attribute__((ext_vector_type(4))) int   i32x4;
typedef __attribute__((ext_vector_type(4))) unsigned int u32x4;

#define CB 256
#define HWN 4096
#define THR 0.5f
#define MAXC 32

// RNE fp32 -> bf16-grid fp32 (final output cast)
static __device__ __forceinline__ float rbf(float x){
  unsigned int u = __builtin_bit_cast(unsigned int, x);
  u = (u + 0x7fffu + ((u >> 16) & 1u)) & 0xffff0000u;
  return __builtin_bit_cast(float, u);
}
// RNE fp32 pair -> packed bf16x2
static __device__ __forceinline__ unsigned int pk2(float a, float b){
  unsigned int ua = __builtin_bit_cast(unsigned int, a);
  unsigned int ub = __builtin_bit_cast(unsigned int, b);
  ua = (ua + 0x7fffu + ((ua >> 16) & 1u)) >> 16;
  ub = (ub + 0x7fffu + ((ub >> 16) & 1u)) & 0xffff0000u;
  return ua | ub;
}
static __device__ __forceinline__ void gld_lds16(const void* g, void* l){
  __builtin_amdgcn_global_load_lds(
      (const __attribute__((address_space(1))) unsigned int*)g,
      (__attribute__((address_space(3))) unsigned int*)l, 16, 0, 0);
}

// ---------------- prep: s2[n] (np-pairwise, r7-proven) + bf16 swizzled staging image
__global__ void vq_prep(const float* __restrict__ wcb, float* __restrict__ s2g,
                        unsigned int* __restrict__ w_swz){
  int n = blockIdx.x * 256 + threadIdx.x;
  const float* row = wcb + (size_t)n * CB;
  float blk[2];
  #pragma unroll
  for (int b2 = 0; b2 < 2; ++b2){
    float r[8];
    #pragma unroll
    for (int k = 0; k < 8; ++k){ float x = row[b2*128 + k]; r[k] = __fmul_rn(x, x); }
    for (int t = 1; t < 16; ++t)
      #pragma unroll
      for (int k = 0; k < 8; ++k){
        float x = row[b2*128 + t*8 + k];
        r[k] = __fadd_rn(r[k], __fmul_rn(x, x));
      }
    blk[b2] = __fadd_rn(__fadd_rn(__fadd_rn(r[0],r[1]), __fadd_rn(r[2],r[3])),
                        __fadd_rn(__fadd_rn(r[4],r[5]), __fadd_rn(r[6],r[7])));
  }
  s2g[n] = __fadd_rn(blk[0], blk[1]);
  // staging image: row n at byte n*512; granule qp holds source granule qp^(n&7)
  {
    unsigned int* dst = w_swz + (size_t)n * 128;
    #pragma unroll
    for (int qp = 0; qp < 32; ++qp){
      int sg = qp ^ (n & 7);
      f32x4 va = *(const f32x4*)(row + sg*8);
      f32x4 vb = *(const f32x4*)(row + sg*8 + 4);
      u32x4 pk = { pk2(va[0],va[1]), pk2(va[2],va[3]), pk2(vb[0],vb[1]), pk2(vb[2],vb[3]) };
      *(u32x4*)(dst + qp*4) = pk;
    }
  }
}

// ---------------- s1: np-pairwise f32 sum of z^2 per position (r7-proven, coalesced)
__global__ void vq_s1(const float* __restrict__ ze, float* __restrict__ s1g){
  int pos = blockIdx.x * 256 + threadIdx.x;
  int b = pos >> 12, hw = pos & 4095;
  const float* zp = ze + (size_t)b * CB * HWN + hw;
  float blk[2];
  #pragma unroll
  for (int b2 = 0; b2 < 2; ++b2){
    float r[8];
    for (int t = 0; t < 16; ++t)
      #pragma unroll
      for (int k = 0; k < 8; ++k){
        float x = zp[(size_t)(b2*128 + t*8 + k) * HWN];
        float q = __fmul_rn(x, x);
        if (t == 0) r[k] = q; else r[k] = __fadd_rn(r[k], q);
      }
    blk[b2] = __fadd_rn(__fadd_rn(__fadd_rn(r[0],r[1]), __fadd_rn(r[2],r[3])),
                        __fadd_rn(__fadd_rn(r[4],r[5]), __fadd_rn(r[6],r[7])));
  }
  s1g[pos] = __fadd_rn(blk[0], blk[1]);
}

// ---------------- screen: pipelined 2-pass MFMA + f64 exact re-rank -> selg
__global__ __launch_bounds__(256, 2)
void vq_screen(const float* __restrict__ ze, const float* __restrict__ wcb,
               const unsigned int* __restrict__ w_swz,
               const float* __restrict__ s2g, const float* __restrict__ s1g,
               int* __restrict__ selg)
{
  __shared__ __align__(16) char smem[65536];  // [0,32K) zeT | [32K,64K) B[2][16K]
  __shared__ float s2l[1024];
  __shared__ float selv[128];
  __shared__ float minl[64];
  __shared__ int   cnt[64];
  __shared__ int   list[64][MAXC];
  __shared__ unsigned int kd[64];
  __shared__ int   ki[64];

  const int tid = threadIdx.x, bid = blockIdx.x;
  const int b = bid >> 6, hw0 = (bid & 63) * 64;
  const int wid = tid >> 6, lane = tid & 63, l15 = lane & 15, lq = lane >> 4;
  const int wr = wid >> 1, wc = wid & 1;
  char* Bbuf = smem + 32768;

  // issue stage of chunk 0 -> buf 0 (hides under phase A)
  {
    const char* src = (const char*)w_swz;
    #pragma unroll
    for (int j = 0; j < 4; ++j)
      gld_lds16(src + (j*256 + tid)*16, Bbuf + (j*256 + wid*64)*16);
  }

  // phase A: raw f32 z -> bf16 zeT (RNE, granule-swizzled); s2 -> LDS
  {
    const int p = tid & 63, cg = tid >> 6;
    const float* zp = ze + (size_t)b * CB * HWN + hw0 + p;
    #pragma unroll
    for (int o = 0; o < 8; ++o){
      int c0 = cg*64 + o*8;
      float v[8];
      #pragma unroll
      for (int i = 0; i < 8; ++i) v[i] = zp[(size_t)(c0 + i) * HWN];
      int g = (c0 >> 3) ^ (p & 7);
      u32x4 pk = { pk2(v[0],v[1]), pk2(v[2],v[3]), pk2(v[4],v[5]), pk2(v[6],v[7]) };
      *(u32x4*)(smem + p*512 + g*16) = pk;
    }
    #pragma unroll
    for (int k = 0; k < 4; ++k) s2l[k*256 + tid] = s2g[k*256 + tid];
  }
  if (tid < 64){ minl[tid] = 3.4e38f; cnt[tid] = 0; }
  asm volatile("s_waitcnt vmcnt(0)" ::: "memory");
  __syncthreads();

  float szr[8];
  {
    const float* s1b = s1g + (size_t)b * HWN + hw0;
    int rowbase = wr*32 + lq*4;
    #pragma unroll
    for (int m = 0; m < 2; ++m)
      #pragma unroll
      for (int r = 0; r < 4; ++r)
        szr[m*4+r] = s1b[rowbase + m*16 + r];
  }

  const int rA0 = wr*32 + l15, rA1 = rA0 + 16, rB = wc*16 + l15;

  float minv[8];
  #pragma unroll
  for (int i = 0; i < 8; ++i) minv[i] = 3.4e38f;
  float thr8[8];

  int cur = 0;
  for (int it = 0; it < 64; ++it){
    const int ch = it & 31;
    if (it < 63){                      // stage next half-chunk into other buffer
      const int nch = (it + 1) & 31;
      const char* src = (const char*)w_swz + (size_t)nch * 16384;
      char* dst = Bbuf + (cur^1)*16384;
      #pragma unroll
      for (int j = 0; j < 4; ++j)
        gld_lds16(src + (j*256 + tid)*16, dst + (j*256 + wid*64)*16);
    }
    float sw = s2l[ch*32 + wc*16 + l15];

    const char* Bc = Bbuf + cur*16384;
    f32x4 acc0 = {0,0,0,0}, acc1 = {0,0,0,0};
    #pragma unroll
    for (int ks = 0; ks < 8; ++ks){
      int gk = ks*4 + lq;
      short8 a0 = *(const short8*)(smem + rA0*512 + ((gk ^ (rA0 & 7)) << 4));
      short8 a1 = *(const short8*)(smem + rA1*512 + ((gk ^ (rA1 & 7)) << 4));
      short8 b0 = *(const short8*)(Bc   + rB*512  + ((gk ^ (rB  & 7)) << 4));
      acc0 = __builtin_amdgcn_mfma_f32_16x16x32_bf16(a0, b0, acc0, 0, 0, 0);
      acc1 = __builtin_amdgcn_mfma_f32_16x16x32_bf16(a1, b0, acc1, 0, 0, 0);
    }

    if (it < 32){                      // pass 1: registers-only min tracking
      #pragma unroll
      for (int m = 0; m < 2; ++m)
        #pragma unroll
        for (int r = 0; r < 4; ++r){
          int i = m*4 + r;
          float e = (m == 0) ? acc0[r] : acc1[r];
          float d = __fsub_rn(__fadd_rn(szr[i], sw), 2.0f*e);
          minv[i] = fminf(minv[i], d);
        }
    } else {                           // pass 2: collect vs final min + THR
      const int c0 = ch*32 + wc*16 + l15;
      #pragma unroll
      for (int m = 0; m < 2; ++m)
        #pragma unroll
        for (int r = 0; r < 4; ++r){
          int i = m*4 + r;
          float e = (m == 0) ? acc0[r] : acc1[r];
          float d = __fsub_rn(__fadd_rn(szr[i], sw), 2.0f*e);
          if (d <= thr8[i]){
            int row = wr*32 + m*16 + lq*4 + r;
            int s = atomicAdd(&cnt[row], 1);
            if (s < MAXC) list[row][s] = c0;
          }
        }
    }

    asm volatile("s_waitcnt vmcnt(0)" ::: "memory");
    __syncthreads();
    cur ^= 1;

    if (it == 31){                     // one-time min finalize (stage for it=32 done)
      #pragma unroll
      for (int i = 0; i < 8; ++i){
        float v = minv[i];
        #pragma unroll
        for (int off = 1; off < 16; off <<= 1) v = fminf(v, __shfl_xor(v, off, 64));
        minv[i] = v;
      }
      if (l15 == 0){
        #pragma unroll
        for (int m = 0; m < 2; ++m)
          #pragma unroll
          for (int r = 0; r < 4; ++r)
            selv[wc*64 + wr*32 + m*16 + lq*4 + r] = minv[m*4+r];
      }
      __syncthreads();
      if (tid < 64) minl[tid] = fminf(selv[tid], selv[64 + tid]);
      __syncthreads();
      {
        int rowbase = wr*32 + lq*4;
        #pragma unroll
        for (int m = 0; m < 2; ++m)
          #pragma unroll
          for (int r = 0; r < 4; ++r)
            thr8[m*4+r] = minl[rowbase + m*16 + r] + THR;
      }
    }
  }

  // ---- exact f64 re-rank (r7-proven), 2-phase atomic pick, write selg
  if (tid < 64){ kd[tid] = 0xffffffffu; ki[tid] = 0x7fffffff; }
  __syncthreads();
  {
    const int pos = tid & 63, sq = tid >> 6;
    const int c_ = min(cnt[pos], MAXC);
    const float* zr = ze + (size_t)b * CB * HWN + hw0 + pos;
    const float s1p = s1g[(size_t)b * HWN + hw0 + pos];
    float dloc[8]; int nl = 0;
    for (int slot = sq; slot < c_; slot += 4){
      int code = list[pos][slot];
      const float* wrow = wcb + (size_t)code * CB;
      double a = 0.0;
      #pragma unroll 8
      for (int c = 0; c < 256; ++c)
        a = fma((double)zr[(size_t)c * HWN], (double)wrow[c], a);
      float e32 = (float)a;
      float d = __fsub_rn(__fadd_rn(s1p, s2l[code]), __fmul_rn(2.0f, e32));
      dloc[nl++] = d;
      atomicMin(&kd[pos], __float_as_uint(d));
    }
    __syncthreads();
    nl = 0;
    for (int slot = sq; slot < c_; slot += 4){
      int code = list[pos][slot];
      if (__float_as_uint(dloc[nl++]) == kd[pos]) atomicMin(&ki[pos], code);
    }
  }
  __syncthreads();
  if (tid < 64){
    int res;
    if (cnt[tid] <= MAXC){
      res = ki[tid];
    } else {                           // overflow fallback (statistically never)
      const float* zr = ze + (size_t)b * CB * HWN + hw0 + tid;
      const float s1p = s1g[(size_t)b * HWN + hw0 + tid];
      float bv = 3.4e38f; res = 0;
      for (int n = 0; n < 1024; ++n){
        double a = 0.0;
        for (int c = 0; c < 256; ++c)
          a = fma((double)zr[(size_t)c * HWN], (double)wcb[(size_t)n * CB + c], a);
        float e32 = (float)a;
        float d = __fsub_rn(__fadd_rn(s1p, s2l[n]), __fmul_rn(2.0f, e32));
        if (d < bv){ bv = d; res = n; }
      }
    }
    selg[(size_t)b * HWN + hw0 + tid] = res;
  }
}

// ---------------- epilogue: streaming STE output + loss partials; one (b,c) row per block
__global__ __launch_bounds__(256)
void vq_epi(const float* __restrict__ ze, const float* __restrict__ wcb,
            const int* __restrict__ selg, float* __restrict__ out,
            float* __restrict__ partial)
{
  __shared__ float red[256];
  const int tid = threadIdx.x, bid = blockIdx.x;
  const int b = bid >> 8, c = bid & 255;
  const float* zrow = ze  + ((size_t)b * CB + c) * HWN;
  float*       orow = out + ((size_t)b * CB + c) * HWN;
  const int*   srow = selg + (size_t)b * HWN;
  float lacc = 0.f;
  #pragma unroll
  for (int k = 0; k < 4; ++k){
    int base = (k*256 + tid) * 4;
    f32x4 z4 = *(const f32x4*)(zrow + base);
    i32x4 s4 = *(const i32x4*)(srow + base);
    f32x4 o4;
    #pragma unroll
    for (int e = 0; e < 4; ++e){
      float zq = wcb[(size_t)s4[e] * CB + c];
      float zf = z4[e];
      float st = __fadd_rn(zf, __fsub_rn(zq, zf));   // f32 STE
      o4[e] = rbf(st);                               // final bf16 cast
      float dd = __fsub_rn(zf, zq);
      lacc = __fadd_rn(lacc, __fmul_rn(dd, dd));
    }
    *(f32x4*)(orow + base) = o4;
  }
  red[tid] = lacc;
  __syncthreads();
  for (int s = 128; s > 0; s >>= 1){
    if (tid < s) red[tid] += red[tid + s];
    __syncthreads();
  }
  if (tid == 0) partial[bid] = red[0];
}

// ---------------- loss: vq[b] = fl(m + fl(0.25*m)), m = fl(sum/2^20); bf16 cast
__global__ void vq_loss(const float* __restrict__ partial, float* __restrict__ outl){
  int t = threadIdx.x;
  if (t < 16){
    float s = 0.f;
    for (int j = 0; j < 256; ++j) s += partial[t*256 + j];
    float m = __fmul_rn(s, 1.0f / 1048576.0f);
    outl[t] = rbf(__fadd_rn(m, __fmul_rn(0.25f, m)));
  }
}

extern "C" void kernel_launch(void* const* d_in, const int* in_sizes, int n_in,
                              void* d_out, int out_size, void* d_ws, size_t ws_size,
                              hipStream_t stream)
{
  const float* ze  = (const float*)d_in[0];   // z_e  [16,256,64,64] raw f32
  const float* wcb = (const float*)d_in[1];   // embed_w [1024,256] raw f32
  float* out = (float*)d_out;                 // z_q_st (bf16-grid f32) + vq_loss[16]
  float* s2g     = (float*)d_ws;              // [1024]
  float* s1g     = s2g + 1024;                // [65536]
  int*   selg    = (int*)(s1g + 65536);       // [65536]
  float* partial = (float*)(selg + 65536);    // [4096]
  unsigned int* w_swz = (unsigned int*)(partial + 4096);  // [1024*128] = 512 KB

  hipLaunchKernelGGL(vq_prep,   dim3(4),    dim3(256), 0, stream, wcb, s2g, w_swz);
  hipLaunchKernelGGL(vq_s1,     dim3(256),  dim3(256), 0, stream, ze, s1g);
  hipLaunchKernelGGL(vq_screen, dim3(1024), dim3(256), 0, stream,
                     ze, wcb, w_swz, s2g, s1g, selg);
  hipLaunchKernelGGL(vq_epi,    dim3(4096), dim3(256), 0, stream,
                     ze, wcb, selg, out, partial);
  hipLaunchKernelGGL(vq_loss,   dim3(1),    dim3(64), 0, stream,
                     partial, out + (size_t)16 * 256 * 4096);
}